// Round 3
// baseline (2203.834 us; speedup 1.0000x reference)
//
#include <hip/hip_runtime.h>

// BiquadCell: o_t = tanh(w0*x0 + w1*x1 + (w2+1)*x2 + w3*o_{t-1} + w4*o_{t-2})
// inputs [T,B,3] f32, carry [B,2] f32, weights [1,5] f32 -> out [T,B,1] f32
//
// Latency-bound serial scan: 1 thread per batch element (2048 threads = 32
// wave64s). State tracked as r = 1/(exp2(K*u)+1), K = 2*log2(e), so o = 1-2r.
// Critical chain per step: fma -> v_exp_f32 -> add -> v_rcp_f32 (~24-32 cy).
// Loads deep-pipelined: 4 register buffers x 16 steps, prefetch distance 3
// chunks (~1250 cy > ~900 cy HBM latency), all statically indexed (rule #20).

constexpr int TT = 16384;
constexpr int BB = 2048;
constexpr int UU = 16;

#define LOADC(i, tb)                                                      \
  if ((tb) < TT) {                                                        \
    const float* _p = xp + (size_t)(tb) * (BB * 3);                       \
    _Pragma("unroll")                                                     \
    for (int u = 0; u < UU; ++u) {                                        \
      bx[i][u][0] = _p[0];                                                \
      bx[i][u][1] = _p[1];                                                \
      bx[i][u][2] = _p[2];                                                \
      _p += BB * 3;                                                       \
    }                                                                     \
  }

#define COMPC(i, tb)                                                      \
  {                                                                       \
    _Pragma("unroll")                                                     \
    for (int u = 0; u < UU; ++u) {                                        \
      float xpart = fmaf(kw0, bx[i][u][0],                                \
                    fmaf(kw1, bx[i][u][1],                                \
                    fmaf(kw2, bx[i][u][2], kc)));                         \
      float base = fmaf(c4, r2, xpart); /* r2 has 2 steps of slack */     \
      float pp = fmaf(c3, r1, base);    /* critical: depends on r1 */     \
      float ee = __builtin_amdgcn_exp2f(pp);   /* v_exp_f32 */            \
      float dd = ee + 1.0f;                                               \
      float rr = __builtin_amdgcn_rcpf(dd);    /* v_rcp_f32 */            \
      float oo = fmaf(-2.0f, rr, 1.0f);                                   \
      __builtin_nontemporal_store(oo, &out[(size_t)((tb) + u) * BB + b]); \
      r2 = r1;                                                            \
      r1 = rr;                                                            \
    }                                                                     \
  }

__global__ __launch_bounds__(64)
__attribute__((amdgpu_waves_per_eu(1)))
void biquad_scan(const float* __restrict__ x,
                 const float* __restrict__ carry,
                 const float* __restrict__ w,
                 float* __restrict__ out) {
  const int b = blockIdx.x * 64 + threadIdx.x;

  const float Kk = 2.8853900817779268f;  // 2*log2(e)
  const float w0 = w[0], w1 = w[1], w2 = w[2], w3 = w[3], w4 = w[4];
  const float kw0 = Kk * w0;
  const float kw1 = Kk * w1;
  const float kw2 = Kk * (w2 + 1.0f);    // +1: skip connection of last tap
  const float c3 = -2.0f * Kk * w3;      // coeff on r_{t-1}
  const float c4 = -2.0f * Kk * w4;      // coeff on r_{t-2}
  const float kc = Kk * (w3 + w4);       // constant from o = 1 - 2r

  // r = (1 - o)/2 ; carry[b][0] = o_{t-1}, carry[b][1] = o_{t-2}
  float r1 = fmaf(-0.5f, carry[2 * b + 0], 0.5f);
  float r2 = fmaf(-0.5f, carry[2 * b + 1], 0.5f);

  const float* xp = x + (size_t)b * 3;

  float bx[4][UU][3];  // 192 VGPRs, statically indexed only

  LOADC(0, 0)
  LOADC(1, UU)
  LOADC(2, 2 * UU)
  for (int t0 = 0; t0 < TT; t0 += 4 * UU) {
    LOADC(3, t0 + 3 * UU)
    COMPC(0, t0)
    LOADC(0, t0 + 4 * UU)
    COMPC(1, t0 + UU)
    LOADC(1, t0 + 5 * UU)
    COMPC(2, t0 + 2 * UU)
    LOADC(2, t0 + 6 * UU)
    COMPC(3, t0 + 3 * UU)
  }
}

extern "C" void kernel_launch(void* const* d_in, const int* in_sizes, int n_in,
                              void* d_out, int out_size, void* d_ws, size_t ws_size,
                              hipStream_t stream) {
  const float* x     = (const float*)d_in[0];
  const float* carry = (const float*)d_in[1];
  const float* w     = (const float*)d_in[2];
  float* out         = (float*)d_out;

  hipLaunchKernelGGL(biquad_scan, dim3(BB / 64), dim3(64), 0, stream,
                     x, carry, w, out);
}